// Round 3
// baseline (418.842 us; speedup 1.0000x reference)
//
#include <hip/hip_runtime.h>

#define AGENT __HIP_MEMORY_SCOPE_AGENT

constexpr int TD = 9, DIN = 135;
constexpr int CAP3 = 256, CAP2 = 1024, CAP1 = 4096, BK = 128;
constexpr int NB = 512;  // mega-kernel grid: 512 blocks x 256 thr; __launch_bounds__(256,2)
                         // guarantees 2 blocks/CU -> all 512 co-resident on 256 CUs.

struct P {
  const float* x; const int* src; const int* dst; int N; int E;
  const float *W_in,*b_in,*g1W,*g1as,*g1ad,*g1b,*g2W,*g2as,*g2ad,*g2b,*g3W,*g3as,*g3ad,*g3b;
  const float *r1W,*r1b,*r2W,*r2b,*r3W,*r3b,*n1g,*n1b,*n2g,*n2b,*n3g,*n3b;
  const float *tw,*c1W,*c1b,*clg,*clb,*c2W,*c2b;
  float* tp;
  int *m3,*m2,*m1,*list3,*list2,*list1,*cnts;  // cnts[0..2]=cnt3/2/1, [8]=simsum(f32), [32]=barCnt, [48]=barGen, [56]=list0
  int *bcnt1,*bcnt2,*bcnt3,*bk1,*bk2,*bk3;
  float *h0,*hh1,*es1,*ed1,*h1,*hh2,*es2,*ed2,*h2,*hh3,*es3,*ed3,*h3;
  float* dout;
};

__device__ __forceinline__ float lrelu(float v) { return v >= 0.f ? v : 0.2f * v; }

// CAS-claim node v into (m, list, cnt). m[v] starts -1.
__device__ __forceinline__ void claim_node(int v, int* __restrict__ m, int* __restrict__ list,
                                           int* __restrict__ cnt, int cap) {
  if (atomicCAS(&m[v], -1, -2) == -1) {
    int pos = atomicAdd(cnt, 1);
    if (pos < cap) { list[pos] = v; m[v] = pos; } else { m[v] = -3; }
  }
}

// device-scope grid barrier; all NB blocks must call the same sequence.
__device__ __forceinline__ void grid_barrier(int* cnt, int* gen, int nblk, int& lgen) {
  __syncthreads();
  if (threadIdx.x == 0) {
    int g = ++lgen;
    __threadfence();                    // release: wbl2 flushes this XCD's dirty L2
    int arrived = __hip_atomic_fetch_add(cnt, 1, __ATOMIC_ACQ_REL, AGENT);
    if (arrived == nblk - 1) {
      __hip_atomic_store(cnt, 0, __ATOMIC_RELAXED, AGENT);
      __hip_atomic_store(gen, g, __ATOMIC_RELEASE, AGENT);
    } else {
      while (__hip_atomic_load(gen, __ATOMIC_RELAXED, AGENT) < g) __builtin_amdgcn_s_sleep(2);
    }
    __threadfence();                    // acquire: inv stale lines before reading others' data
  }
  __syncthreads();
}

// init: maps=-1, counters/barrier=0, bucket counts=0, pack t = x[:,126:135]
__global__ void k_init(P p) {
  int gt = blockIdx.x * blockDim.x + threadIdx.x;
  int GT = gridDim.x * blockDim.x;
  int n3 = 3 * p.N;
  int4* mv = (int4*)p.m3;             // m3,m2,m1 contiguous
  int4 neg = make_int4(-1, -1, -1, -1);
  int nv = n3 >> 2;
  for (int i = gt; i < nv; i += GT) mv[i] = neg;
  for (int i = (nv << 2) + gt; i < n3; i += GT) p.m3[i] = -1;
  if (gt < 64) p.cnts[gt] = 0;
  for (int i = gt; i < CAP2; i += GT) p.bcnt1[i] = 0;
  for (int i = gt; i < CAP3; i += GT) p.bcnt2[i] = 0;
  if (gt == 0) p.bcnt3[0] = 0;
  int total = p.N * TD;
  for (int i = gt; i < total; i += GT) {
    int v = i / TD, k = i - v * TD;
    p.tp[i] = p.x[(size_t)v * DIN + (DIN - TD) + k];
  }
}

// GAT layer for a compacted dst set (one block per dst node, 256 threads).
// Includes appended self-loop, head-mean+bias, optional scale, relu+residual GEMV, LN,
// and fused next-layer projection (ONEXT>0).
template <int C, int ONEXT>
__device__ void gat_phase(int nq, const int* lst, const int* mPrev,
                          const int* bket, const int* bcnt,
                          const float* hh, const float* es, const float* ed, const float* hres,
                          const float* gb, const float* rW, const float* rb,
                          const float* ng, const float* nbv, float scale,
                          float* hout, const float* Wn, const float* avn, const float* bvn,
                          float* hhn, float* esn, float* edn,
                          float* elog, int* eposs, float* sh, float* hres_s, float* shln,
                          float* psn, float* pdn, float* sc2, float* ev_s) {
  const int T = 256, Wd = 4 * C, R = Wd / T;
  int tid = threadIdx.x;
  for (int q = blockIdx.x; q < nq; q += gridDim.x) {
    int v = lst[q];
    int sp = mPrev[v];
    int nb = min(bcnt[q], BK);
    for (int j = tid; j < nb; j += T) {
      int pu = mPrev[bket[(size_t)q * BK + j]];
      eposs[j] = pu;
      const float* ep = &es[(size_t)pu * 4];
      elog[0 * BK + j] = ep[0]; elog[1 * BK + j] = ep[1];
      elog[2 * BK + j] = ep[2]; elog[3 * BK + j] = ep[3];
    }
    if (tid < 4) { ev_s[tid] = es[(size_t)sp * 4 + tid]; ev_s[4 + tid] = ed[(size_t)sp * 4 + tid]; }
    for (int k = tid; k < 128; k += T) hres_s[k] = hres[(size_t)sp * 128 + k];
    __syncthreads();
#pragma unroll
    for (int r = 0; r < R; r++) {
      int w = r * T + tid, a = w / C;
      float edv = ev_s[4 + a];
      float eself = lrelu(ev_s[a] + edv);
      float mx = eself;
      for (int j = 0; j < nb; j++) mx = fmaxf(mx, lrelu(elog[a * BK + j] + edv));
      float den = __expf(eself - mx);
      for (int j = 0; j < nb; j++) den += __expf(lrelu(elog[a * BK + j] + edv) - mx);
      float rden = 1.f / (den + 1e-16f);
      float s = __expf(eself - mx) * rden * hh[(size_t)sp * Wd + w];
      for (int j = 0; j < nb; j++)
        s += __expf(lrelu(elog[a * BK + j] + edv) - mx) * rden * hh[(size_t)eposs[j] * Wd + w];
      sh[w] = s;
    }
    __syncthreads();
    float val = 0.f;
    if (tid < C) {
      float g = 0.25f * (sh[tid] + sh[C + tid] + sh[2 * C + tid] + sh[3 * C + tid]) + gb[tid];
      g *= scale;
      g = fmaxf(g, 0.f);
      float rr = rb[tid];
      for (int k = 0; k < 128; k++) rr += hres_s[k] * rW[(size_t)k * C + tid];
      val = g + rr;
      shln[tid] = val;
    }
    __syncthreads();
    if (tid == 0) {
      float s1 = 0.f, s2 = 0.f;
      for (int k = 0; k < C; k++) { float u = shln[k]; s1 += u; s2 += u * u; }
      float mu = s1 / (float)C;
      sc2[0] = mu;
      sc2[1] = rsqrtf(fmaxf(s2 / (float)C - mu * mu, 0.f) + 1e-5f);
    }
    __syncthreads();
    if (tid < C) {
      float o = (val - sc2[0]) * sc2[1] * ng[tid] + nbv[tid];
      hout[(size_t)q * C + tid] = o;
      shln[tid] = o;
    }
    __syncthreads();
    if (ONEXT > 0) {
      for (int j = tid; j < ONEXT; j += T) {
        float a2 = 0.f;
        for (int k = 0; k < C; k++) a2 += shln[k] * Wn[(size_t)k * ONEXT + j];
        hhn[(size_t)q * ONEXT + j] = a2;
        psn[j] = a2 * avn[j]; pdn[j] = a2 * bvn[j];
      }
      __syncthreads();
      if (tid < 8) {
        const int CN = ONEXT / 4; int a = tid & 3;
        const float* pr = (tid < 4) ? psn : pdn;
        float s = 0.f;
        for (int c = 0; c < CN; c++) s += pr[a * CN + c];
        (tid < 4 ? esn : edn)[(size_t)q * 4 + a] = s;
      }
    }
    __syncthreads();
  }
}

__global__ __launch_bounds__(256, 2) void k_mega(P p) {
  __shared__ float elog[4 * BK];
  __shared__ int   eposs[BK];
  __shared__ float sh[512];
  __shared__ float hres_s[128];
  __shared__ float shln[128];
  __shared__ float psn[512], pdn[512];
  __shared__ float xs[DIN + 1];
  __shared__ float sc2[2];
  __shared__ float ev_s[8];
  __shared__ float wred[4];
  __shared__ float zcl[64];

  int tid = threadIdx.x, bid = blockIdx.x;
  int gt = bid * 256 + tid, GT = gridDim.x * 256;
  int lgen = 0;
  int* barc = &p.cnts[32];
  int* barg = &p.cnts[48];
  float* simsum = (float*)&p.cnts[8];

  // ---- P1: cosine-sim over all E edges + claim S3 = {0} U N_in(0) ----
  {
    if (gt == 0) claim_node(0, p.m3, p.list3, &p.cnts[0], CAP3);
    float local = 0.f;
    for (int e = gt; e < p.E; e += GT) {
      int s = p.src[e], d = p.dst[e];
      if (d == 0) claim_node(s, p.m3, p.list3, &p.cnts[0], CAP3);
      const float* ti = p.tp + (size_t)s * TD;
      const float* tj = p.tp + (size_t)d * TD;
      float dot = 0.f, na = 0.f, nb2 = 0.f;
#pragma unroll
      for (int k = 0; k < TD; k++) { float a = ti[k], b = tj[k]; dot += a * b; na += a * a; nb2 += b * b; }
      local += dot / (fmaxf(sqrtf(na), 1e-8f) * fmaxf(sqrtf(nb2), 1e-8f));
    }
    for (int off = 32; off > 0; off >>= 1) local += __shfl_down(local, off, 64);
    if ((tid & 63) == 0) wred[tid >> 6] = local;
    __syncthreads();
    if (tid == 0) atomicAdd(simsum, wred[0] + wred[1] + wred[2] + wred[3]);
  }
  grid_barrier(barc, barg, gridDim.x, lgen);

  // ---- P2: claim S2 = S3 U N_in(S3) ----
  {
    int c3 = min(__hip_atomic_load(&p.cnts[0], __ATOMIC_RELAXED, AGENT), CAP3);
    for (int i = gt; i < c3; i += GT) claim_node(p.list3[i], p.m2, p.list2, &p.cnts[1], CAP2);
    for (int e = gt; e < p.E; e += GT)
      if (p.m3[p.dst[e]] >= 0) claim_node(p.src[e], p.m2, p.list2, &p.cnts[1], CAP2);
  }
  grid_barrier(barc, barg, gridDim.x, lgen);

  // ---- P3: claim S1 = S2 U N_in(S2), and build per-dst edge buckets (raw src ids) ----
  {
    int c2 = min(__hip_atomic_load(&p.cnts[1], __ATOMIC_RELAXED, AGENT), CAP2);
    for (int i = gt; i < c2; i += GT) claim_node(p.list2[i], p.m1, p.list1, &p.cnts[2], CAP1);
    for (int e = gt; e < p.E; e += GT) {
      int s = p.src[e], d = p.dst[e];
      int p2 = p.m2[d];
      if (p2 >= 0) {
        claim_node(s, p.m1, p.list1, &p.cnts[2], CAP1);
        int sl = atomicAdd(&p.bcnt1[p2], 1); if (sl < BK) p.bk1[(size_t)p2 * BK + sl] = s;
      }
      int p3 = p.m3[d];
      if (p3 >= 0) { int sl = atomicAdd(&p.bcnt2[p3], 1); if (sl < BK) p.bk2[(size_t)p3 * BK + sl] = s; }
      if (d == 0)  { int sl = atomicAdd(&p.bcnt3[0], 1);  if (sl < BK) p.bk3[sl] = s; }
    }
  }
  grid_barrier(barc, barg, gridDim.x, lgen);

  // ---- P4: per S1 node: h0 = x@W_in+b_in ; hh1 = h0@g1W ; es1/ed1 head sums ----
  {
    int c1 = min(__hip_atomic_load(&p.cnts[2], __ATOMIC_RELAXED, AGENT), CAP1);
    for (int pp = bid; pp < c1; pp += gridDim.x) {
      int v = p.list1[pp];
      for (int k = tid; k < DIN; k += 256) xs[k] = p.x[(size_t)v * DIN + k];
      __syncthreads();
      if (tid < 128) {
        float acc = p.b_in[tid];
        for (int k = 0; k < DIN; k++) acc += xs[k] * p.W_in[(size_t)k * 128 + tid];
        p.h0[(size_t)pp * 128 + tid] = acc;
        hres_s[tid] = acc;
      }
      __syncthreads();
#pragma unroll
      for (int jj = 0; jj < 2; jj++) {
        int j = jj * 256 + tid;
        float acc = 0.f;
        for (int k = 0; k < 128; k++) acc += hres_s[k] * p.g1W[(size_t)k * 512 + j];
        p.hh1[(size_t)pp * 512 + j] = acc;
        psn[j] = acc * p.g1as[j]; pdn[j] = acc * p.g1ad[j];
      }
      __syncthreads();
      if (tid < 8) {
        int a = tid & 3;
        const float* pr = (tid < 4) ? psn : pdn;
        float s = 0.f;
        for (int c = 0; c < 128; c++) s += pr[a * 128 + c];
        (tid < 4 ? p.es1 : p.ed1)[(size_t)pp * 4 + a] = s;
      }
      __syncthreads();
    }
  }
  grid_barrier(barc, barg, gridDim.x, lgen);

  int sbits = __hip_atomic_load(&p.cnts[8], __ATOMIC_RELAXED, AGENT);
  float scale = 1.1f + 0.1f * p.tw[0] * __int_as_float(sbits) / (float)p.E;

  // ---- P5: GAT1 over S2 (+ fused proj2) ----
  {
    int c2 = min(__hip_atomic_load(&p.cnts[1], __ATOMIC_RELAXED, AGENT), CAP2);
    gat_phase<128, 512>(c2, p.list2, p.m1, p.bk1, p.bcnt1,
                        p.hh1, p.es1, p.ed1, p.h0,
                        p.g1b, p.r1W, p.r1b, p.n1g, p.n1b, scale,
                        p.h1, p.g2W, p.g2as, p.g2ad, p.hh2, p.es2, p.ed2,
                        elog, eposs, sh, hres_s, shln, psn, pdn, sc2, ev_s);
  }
  grid_barrier(barc, barg, gridDim.x, lgen);

  // ---- P6: GAT2 over S3 (+ fused proj3) ----
  {
    int c3 = min(__hip_atomic_load(&p.cnts[0], __ATOMIC_RELAXED, AGENT), CAP3);
    gat_phase<128, 256>(c3, p.list3, p.m2, p.bk2, p.bcnt2,
                        p.hh2, p.es2, p.ed2, p.h1,
                        p.g2b, p.r2W, p.r2b, p.n2g, p.n2b, scale,
                        p.h2, p.g3W, p.g3as, p.g3ad, p.hh3, p.es3, p.ed3,
                        elog, eposs, sh, hres_s, shln, psn, pdn, sc2, ev_s);
  }
  grid_barrier(barc, barg, gridDim.x, lgen);

  // ---- P7: GAT3 for node 0 only + classifier (block 0) ----
  {
    gat_phase<64, 0>(1, &p.cnts[56] /* ==0 */, p.m3, p.bk3, p.bcnt3,
                     p.hh3, p.es3, p.ed3, p.h2,
                     p.g3b, p.r3W, p.r3b, p.n3g, p.n3b, 1.f,
                     p.h3, nullptr, nullptr, nullptr, nullptr, nullptr, nullptr,
                     elog, eposs, sh, hres_s, shln, psn, pdn, sc2, ev_s);
    if (bid == 0) {
      if (tid < 64) {
        float az = p.c1b[tid];
        for (int k = 0; k < 64; k++) az += shln[k] * p.c1W[k * 64 + tid];
        zcl[tid] = fmaxf(az, 0.f);
      }
      __syncthreads();
      if (tid == 0) {
        float s1 = 0.f, s2 = 0.f;
        for (int k = 0; k < 64; k++) { float u = zcl[k]; s1 += u; s2 += u * u; }
        float mu = s1 / 64.f;
        float rstd = rsqrtf(fmaxf(s2 / 64.f - mu * mu, 0.f) + 1e-5f);
        float o0 = p.c2b[0], o1 = p.c2b[1];
        for (int k = 0; k < 64; k++) {
          float zn = (zcl[k] - mu) * rstd * p.clg[k] + p.clb[k];
          o0 += zn * p.c2W[k * 2 + 0];
          o1 += zn * p.c2W[k * 2 + 1];
        }
        p.dout[0] = o0; p.dout[1] = o1;
      }
    }
  }
}

extern "C" void kernel_launch(void* const* d_in, const int* in_sizes, int n_in,
                              void* d_out, int out_size, void* d_ws, size_t ws_size,
                              hipStream_t stream) {
  P p;
  p.x = (const float*)d_in[0];
  const int* ei = (const int*)d_in[1];
  p.N = in_sizes[0] / DIN;
  p.E = in_sizes[1] / 2;
  p.src = ei; p.dst = ei + p.E;
  p.W_in = (const float*)d_in[3]; p.b_in = (const float*)d_in[4];
  p.g1W = (const float*)d_in[5]; p.g1as = (const float*)d_in[6]; p.g1ad = (const float*)d_in[7]; p.g1b = (const float*)d_in[8];
  p.g2W = (const float*)d_in[9]; p.g2as = (const float*)d_in[10]; p.g2ad = (const float*)d_in[11]; p.g2b = (const float*)d_in[12];
  p.g3W = (const float*)d_in[13]; p.g3as = (const float*)d_in[14]; p.g3ad = (const float*)d_in[15]; p.g3b = (const float*)d_in[16];
  p.r1W = (const float*)d_in[17]; p.r1b = (const float*)d_in[18];
  p.r2W = (const float*)d_in[19]; p.r2b = (const float*)d_in[20];
  p.r3W = (const float*)d_in[21]; p.r3b = (const float*)d_in[22];
  p.n1g = (const float*)d_in[23]; p.n1b = (const float*)d_in[24];
  p.n2g = (const float*)d_in[25]; p.n2b = (const float*)d_in[26];
  p.n3g = (const float*)d_in[27]; p.n3b = (const float*)d_in[28];
  p.tw  = (const float*)d_in[29];
  p.c1W = (const float*)d_in[30]; p.c1b = (const float*)d_in[31];
  p.clg = (const float*)d_in[32]; p.clb = (const float*)d_in[33];
  p.c2W = (const float*)d_in[34]; p.c2b = (const float*)d_in[35];
  p.dout = (float*)d_out;

  char* B = (char*)d_ws;
  size_t off = 0;
  auto take = [&](size_t nbytes) -> char* {
    char* r = B + off;
    off += (nbytes + 255) & ~(size_t)255;
    return r;
  };
  p.cnts  = (int*)take(256);
  p.m3    = (int*)take((size_t)3 * p.N * 4);
  p.m2 = p.m3 + p.N; p.m1 = p.m2 + p.N;
  p.tp    = (float*)take((size_t)p.N * TD * 4);
  p.list3 = (int*)take(CAP3 * 4);
  p.list2 = (int*)take(CAP2 * 4);
  p.list1 = (int*)take(CAP1 * 4);
  p.bcnt1 = (int*)take(CAP2 * 4);
  p.bcnt2 = (int*)take(CAP3 * 4);
  p.bcnt3 = (int*)take(64);
  p.bk1   = (int*)take((size_t)CAP2 * BK * 4);
  p.bk2   = (int*)take((size_t)CAP3 * BK * 4);
  p.bk3   = (int*)take(BK * 4);
  p.h0    = (float*)take((size_t)CAP1 * 128 * 4);
  p.hh1   = (float*)take((size_t)CAP1 * 512 * 4);
  p.es1   = (float*)take((size_t)CAP1 * 16);
  p.ed1   = (float*)take((size_t)CAP1 * 16);
  p.h1    = (float*)take((size_t)CAP2 * 128 * 4);
  p.hh2   = (float*)take((size_t)CAP2 * 512 * 4);
  p.es2   = (float*)take((size_t)CAP2 * 16);
  p.ed2   = (float*)take((size_t)CAP2 * 16);
  p.h2    = (float*)take((size_t)CAP3 * 128 * 4);
  p.hh3   = (float*)take((size_t)CAP3 * 256 * 4);
  p.es3   = (float*)take((size_t)CAP3 * 16);
  p.ed3   = (float*)take((size_t)CAP3 * 16);
  p.h3    = (float*)take(64 * 4);

  k_init<<<1024, 256, 0, stream>>>(p);
  k_mega<<<NB, 256, 0, stream>>>(p);
}

// Round 4
// 178.267 us; speedup vs baseline: 2.3495x; 2.3495x over previous
//
#include <hip/hip_runtime.h>

#define AGENT __HIP_MEMORY_SCOPE_AGENT

constexpr int TD = 9, DIN = 135;
constexpr int CAP3 = 256, CAP2 = 1024, CAP1 = 4096, BK = 128;
constexpr int NB = 512;   // 512 blocks x 256 thr; __launch_bounds__(256,2) -> 2 blocks/CU, all co-resident
constexpr int NLINE = 64, LSTRIDE = 32;   // 64 release lines, 128B apart; 8 pollers/line
constexpr int NBAR = 8;                   // distinct arrival counters (>= barriers used)

struct P {
  const float* x; const int* src; const int* dst; int N; int E;
  const float *W_in,*b_in,*g1W,*g1as,*g1ad,*g1b,*g2W,*g2as,*g2ad,*g2b,*g3W,*g3as,*g3ad,*g3b;
  const float *r1W,*r1b,*r2W,*r2b,*r3W,*r3b,*n1g,*n1b,*n2g,*n2b,*n3g,*n3b;
  const float *tw,*c1W,*c1b,*clg,*clb,*c2W,*c2b;
  float* tp;
  int *m3,*m2,*m1,*list3,*list2,*list1,*cnts;  // cnts[0..2]=cnt3/2/1, [8]=simsum(f32), [56]=const 0
  int *barc, *barg;                            // barc[NBAR*LSTRIDE], barg[NLINE*LSTRIDE]
  int *bcnt1,*bcnt2,*bcnt3,*bk1,*bk2,*bk3;
  float *h0,*hh1,*es1,*ed1,*h1,*hh2,*es2,*ed2,*h2,*hh3,*es3,*ed3,*h3;
  float* dout;
};

__device__ __forceinline__ float lrelu(float v) { return v >= 0.f ? v : 0.2f * v; }

// CAS-claim node v into (m, list, cnt). m[v] starts -1.
__device__ __forceinline__ void claim_node(int v, int* __restrict__ m, int* __restrict__ list,
                                           int* __restrict__ cnt, int cap) {
  if (atomicCAS(&m[v], -1, -2) == -1) {
    int pos = atomicAdd(cnt, 1);
    if (pos < cap) { list[pos] = v; m[v] = pos; } else { m[v] = -3; }
  }
}

// Low-contention device-scope grid barrier.
// Arrival: ACQ_REL RMW (release side flushes this XCD's dirty L2 -> memory).
// Release: last arriver stores gen to 64 spread lines (relaxed, write-through).
// Wait: poll own line (relaxed, bypassing loads) with s_sleep backoff, then acquire fence (inv).
__device__ __forceinline__ void grid_barrier(const P& p, int nblk, int& lgen) {
  __syncthreads();
  if (threadIdx.x == 0) {
    int g = ++lgen;
    int* cnt = &p.barc[(g & (NBAR - 1)) * LSTRIDE];
    int arrived = __hip_atomic_fetch_add(cnt, 1, __ATOMIC_ACQ_REL, AGENT);
    if (arrived == nblk - 1) {
#pragma unroll
      for (int gi = 0; gi < NLINE; ++gi)
        __hip_atomic_store(&p.barg[gi * LSTRIDE], g, __ATOMIC_RELAXED, AGENT);
    } else {
      int* line = &p.barg[(blockIdx.x & (NLINE - 1)) * LSTRIDE];
      while (__hip_atomic_load(line, __ATOMIC_RELAXED, AGENT) < g)
        __builtin_amdgcn_s_sleep(32);
      __builtin_amdgcn_fence(__ATOMIC_ACQUIRE, "agent");   // inv stale L1/L2 lines
    }
  }
  __syncthreads();
}

// init: maps=-1, counters/barrier state=0, bucket counts=0, pack t = x[:,126:135]
__global__ void k_init(P p) {
  int gt = blockIdx.x * blockDim.x + threadIdx.x;
  int GT = gridDim.x * blockDim.x;
  int n3 = 3 * p.N;
  int4* mv = (int4*)p.m3;             // m3,m2,m1 contiguous
  int4 neg = make_int4(-1, -1, -1, -1);
  int nv = n3 >> 2;
  for (int i = gt; i < nv; i += GT) mv[i] = neg;
  for (int i = (nv << 2) + gt; i < n3; i += GT) p.m3[i] = -1;
  if (gt < 64) p.cnts[gt] = 0;
  if (gt < NBAR * LSTRIDE) p.barc[gt] = 0;
  if (gt < NLINE * LSTRIDE) p.barg[gt] = 0;
  for (int i = gt; i < CAP2; i += GT) p.bcnt1[i] = 0;
  for (int i = gt; i < CAP3; i += GT) p.bcnt2[i] = 0;
  if (gt == 0) p.bcnt3[0] = 0;
  int total = p.N * TD;
  for (int i = gt; i < total; i += GT) {
    int v = i / TD, k = i - v * TD;
    p.tp[i] = p.x[(size_t)v * DIN + (DIN - TD) + k];
  }
}

// GAT layer for a compacted dst set (one block per dst node, 256 threads).
template <int C, int ONEXT>
__device__ void gat_phase(int nq, const int* lst, const int* mPrev,
                          const int* bket, const int* bcnt,
                          const float* hh, const float* es, const float* ed, const float* hres,
                          const float* gb, const float* rW, const float* rb,
                          const float* ng, const float* nbv, float scale,
                          float* hout, const float* Wn, const float* avn, const float* bvn,
                          float* hhn, float* esn, float* edn,
                          float* elog, int* eposs, float* sh, float* hres_s, float* shln,
                          float* psn, float* pdn, float* sc2, float* ev_s) {
  const int T = 256, Wd = 4 * C, R = Wd / T;
  int tid = threadIdx.x;
  for (int q = blockIdx.x; q < nq; q += gridDim.x) {
    int v = lst[q];
    int sp = mPrev[v];
    int nb = min(bcnt[q], BK);
    for (int j = tid; j < nb; j += T) {
      int pu = mPrev[bket[(size_t)q * BK + j]];
      eposs[j] = pu;
      const float* ep = &es[(size_t)pu * 4];
      elog[0 * BK + j] = ep[0]; elog[1 * BK + j] = ep[1];
      elog[2 * BK + j] = ep[2]; elog[3 * BK + j] = ep[3];
    }
    if (tid < 4) { ev_s[tid] = es[(size_t)sp * 4 + tid]; ev_s[4 + tid] = ed[(size_t)sp * 4 + tid]; }
    for (int k = tid; k < 128; k += T) hres_s[k] = hres[(size_t)sp * 128 + k];
    __syncthreads();
#pragma unroll
    for (int r = 0; r < R; r++) {
      int w = r * T + tid, a = w / C;
      float edv = ev_s[4 + a];
      float eself = lrelu(ev_s[a] + edv);
      float mx = eself;
      for (int j = 0; j < nb; j++) mx = fmaxf(mx, lrelu(elog[a * BK + j] + edv));
      float den = __expf(eself - mx);
      for (int j = 0; j < nb; j++) den += __expf(lrelu(elog[a * BK + j] + edv) - mx);
      float rden = 1.f / (den + 1e-16f);
      float s = __expf(eself - mx) * rden * hh[(size_t)sp * Wd + w];
      for (int j = 0; j < nb; j++)
        s += __expf(lrelu(elog[a * BK + j] + edv) - mx) * rden * hh[(size_t)eposs[j] * Wd + w];
      sh[w] = s;
    }
    __syncthreads();
    float val = 0.f;
    if (tid < C) {
      float g = 0.25f * (sh[tid] + sh[C + tid] + sh[2 * C + tid] + sh[3 * C + tid]) + gb[tid];
      g *= scale;
      g = fmaxf(g, 0.f);
      float rr = rb[tid];
      for (int k = 0; k < 128; k++) rr += hres_s[k] * rW[(size_t)k * C + tid];
      val = g + rr;
      shln[tid] = val;
    }
    __syncthreads();
    if (tid == 0) {
      float s1 = 0.f, s2 = 0.f;
      for (int k = 0; k < C; k++) { float u = shln[k]; s1 += u; s2 += u * u; }
      float mu = s1 / (float)C;
      sc2[0] = mu;
      sc2[1] = rsqrtf(fmaxf(s2 / (float)C - mu * mu, 0.f) + 1e-5f);
    }
    __syncthreads();
    if (tid < C) {
      float o = (val - sc2[0]) * sc2[1] * ng[tid] + nbv[tid];
      hout[(size_t)q * C + tid] = o;
      shln[tid] = o;
    }
    __syncthreads();
    if (ONEXT > 0) {
      for (int j = tid; j < ONEXT; j += T) {
        float a2 = 0.f;
        for (int k = 0; k < C; k++) a2 += shln[k] * Wn[(size_t)k * ONEXT + j];
        hhn[(size_t)q * ONEXT + j] = a2;
        psn[j] = a2 * avn[j]; pdn[j] = a2 * bvn[j];
      }
      __syncthreads();
      if (tid < 8) {
        const int CN = ONEXT / 4; int a = tid & 3;
        const float* pr = (tid < 4) ? psn : pdn;
        float s = 0.f;
        for (int c = 0; c < CN; c++) s += pr[a * CN + c];
        (tid < 4 ? esn : edn)[(size_t)q * 4 + a] = s;
      }
    }
    __syncthreads();
  }
}

__global__ __launch_bounds__(256, 2) void k_mega(P p) {
  __shared__ float elog[4 * BK];
  __shared__ int   eposs[BK];
  __shared__ float sh[512];
  __shared__ float hres_s[128];
  __shared__ float shln[128];
  __shared__ float psn[512], pdn[512];
  __shared__ float xs[DIN + 1];
  __shared__ float sc2[2];
  __shared__ float ev_s[8];
  __shared__ float wred[4];
  __shared__ float zcl[64];

  int tid = threadIdx.x, bid = blockIdx.x;
  int gt = bid * 256 + tid, GT = gridDim.x * 256;
  int lgen = 0;
  float* simsum = (float*)&p.cnts[8];

  // ---- P1: cosine-sim over all E edges + claim S3 = {0} U N_in(0) ----
  {
    if (gt == 0) claim_node(0, p.m3, p.list3, &p.cnts[0], CAP3);
    float local = 0.f;
    for (int e = gt; e < p.E; e += GT) {
      int s = p.src[e], d = p.dst[e];
      if (d == 0) claim_node(s, p.m3, p.list3, &p.cnts[0], CAP3);
      const float* ti = p.tp + (size_t)s * TD;
      const float* tj = p.tp + (size_t)d * TD;
      float dot = 0.f, na = 0.f, nb2 = 0.f;
#pragma unroll
      for (int k = 0; k < TD; k++) { float a = ti[k], b = tj[k]; dot += a * b; na += a * a; nb2 += b * b; }
      local += dot / (fmaxf(sqrtf(na), 1e-8f) * fmaxf(sqrtf(nb2), 1e-8f));
    }
    for (int off = 32; off > 0; off >>= 1) local += __shfl_down(local, off, 64);
    if ((tid & 63) == 0) wred[tid >> 6] = local;
    __syncthreads();
    if (tid == 0) atomicAdd(simsum, wred[0] + wred[1] + wred[2] + wred[3]);
  }
  grid_barrier(p, gridDim.x, lgen);

  // ---- P2: claim S2 = S3 U N_in(S3) ----
  {
    int c3 = min(__hip_atomic_load(&p.cnts[0], __ATOMIC_RELAXED, AGENT), CAP3);
    for (int i = gt; i < c3; i += GT) claim_node(p.list3[i], p.m2, p.list2, &p.cnts[1], CAP2);
    for (int e = gt; e < p.E; e += GT)
      if (p.m3[p.dst[e]] >= 0) claim_node(p.src[e], p.m2, p.list2, &p.cnts[1], CAP2);
  }
  grid_barrier(p, gridDim.x, lgen);

  // ---- P3: claim S1 = S2 U N_in(S2), and build per-dst edge buckets (raw src ids) ----
  {
    int c2 = min(__hip_atomic_load(&p.cnts[1], __ATOMIC_RELAXED, AGENT), CAP2);
    for (int i = gt; i < c2; i += GT) claim_node(p.list2[i], p.m1, p.list1, &p.cnts[2], CAP1);
    for (int e = gt; e < p.E; e += GT) {
      int s = p.src[e], d = p.dst[e];
      int p2 = p.m2[d];
      if (p2 >= 0) {
        claim_node(s, p.m1, p.list1, &p.cnts[2], CAP1);
        int sl = atomicAdd(&p.bcnt1[p2], 1); if (sl < BK) p.bk1[(size_t)p2 * BK + sl] = s;
      }
      int p3 = p.m3[d];
      if (p3 >= 0) { int sl = atomicAdd(&p.bcnt2[p3], 1); if (sl < BK) p.bk2[(size_t)p3 * BK + sl] = s; }
      if (d == 0)  { int sl = atomicAdd(&p.bcnt3[0], 1);  if (sl < BK) p.bk3[sl] = s; }
    }
  }
  grid_barrier(p, gridDim.x, lgen);

  // ---- P4: per S1 node: h0 = x@W_in+b_in ; hh1 = h0@g1W ; es1/ed1 head sums ----
  {
    int c1 = min(__hip_atomic_load(&p.cnts[2], __ATOMIC_RELAXED, AGENT), CAP1);
    for (int pp = bid; pp < c1; pp += gridDim.x) {
      int v = p.list1[pp];
      for (int k = tid; k < DIN; k += 256) xs[k] = p.x[(size_t)v * DIN + k];
      __syncthreads();
      if (tid < 128) {
        float acc = p.b_in[tid];
        for (int k = 0; k < DIN; k++) acc += xs[k] * p.W_in[(size_t)k * 128 + tid];
        p.h0[(size_t)pp * 128 + tid] = acc;
        hres_s[tid] = acc;
      }
      __syncthreads();
#pragma unroll
      for (int jj = 0; jj < 2; jj++) {
        int j = jj * 256 + tid;
        float acc = 0.f;
        for (int k = 0; k < 128; k++) acc += hres_s[k] * p.g1W[(size_t)k * 512 + j];
        p.hh1[(size_t)pp * 512 + j] = acc;
        psn[j] = acc * p.g1as[j]; pdn[j] = acc * p.g1ad[j];
      }
      __syncthreads();
      if (tid < 8) {
        int a = tid & 3;
        const float* pr = (tid < 4) ? psn : pdn;
        float s = 0.f;
        for (int c = 0; c < 128; c++) s += pr[a * 128 + c];
        (tid < 4 ? p.es1 : p.ed1)[(size_t)pp * 4 + a] = s;
      }
      __syncthreads();
    }
  }
  grid_barrier(p, gridDim.x, lgen);

  int sbits = __hip_atomic_load(&p.cnts[8], __ATOMIC_RELAXED, AGENT);
  float scale = 1.1f + 0.1f * p.tw[0] * __int_as_float(sbits) / (float)p.E;

  // ---- P5: GAT1 over S2 (+ fused proj2) ----
  {
    int c2 = min(__hip_atomic_load(&p.cnts[1], __ATOMIC_RELAXED, AGENT), CAP2);
    gat_phase<128, 512>(c2, p.list2, p.m1, p.bk1, p.bcnt1,
                        p.hh1, p.es1, p.ed1, p.h0,
                        p.g1b, p.r1W, p.r1b, p.n1g, p.n1b, scale,
                        p.h1, p.g2W, p.g2as, p.g2ad, p.hh2, p.es2, p.ed2,
                        elog, eposs, sh, hres_s, shln, psn, pdn, sc2, ev_s);
  }
  grid_barrier(p, gridDim.x, lgen);

  // ---- P6: GAT2 over S3 (+ fused proj3) ----
  {
    int c3 = min(__hip_atomic_load(&p.cnts[0], __ATOMIC_RELAXED, AGENT), CAP3);
    gat_phase<128, 256>(c3, p.list3, p.m2, p.bk2, p.bcnt2,
                        p.hh2, p.es2, p.ed2, p.h1,
                        p.g2b, p.r2W, p.r2b, p.n2g, p.n2b, scale,
                        p.h2, p.g3W, p.g3as, p.g3ad, p.hh3, p.es3, p.ed3,
                        elog, eposs, sh, hres_s, shln, psn, pdn, sc2, ev_s);
  }
  grid_barrier(p, gridDim.x, lgen);

  // ---- P7: GAT3 for node 0 only + classifier (block 0) ----
  {
    gat_phase<64, 0>(1, &p.cnts[56] /* ==0 */, p.m3, p.bk3, p.bcnt3,
                     p.hh3, p.es3, p.ed3, p.h2,
                     p.g3b, p.r3W, p.r3b, p.n3g, p.n3b, 1.f,
                     p.h3, nullptr, nullptr, nullptr, nullptr, nullptr, nullptr,
                     elog, eposs, sh, hres_s, shln, psn, pdn, sc2, ev_s);
    if (bid == 0) {
      if (tid < 64) {
        float az = p.c1b[tid];
        for (int k = 0; k < 64; k++) az += shln[k] * p.c1W[k * 64 + tid];
        zcl[tid] = fmaxf(az, 0.f);
      }
      __syncthreads();
      if (tid == 0) {
        float s1 = 0.f, s2 = 0.f;
        for (int k = 0; k < 64; k++) { float u = zcl[k]; s1 += u; s2 += u * u; }
        float mu = s1 / 64.f;
        float rstd = rsqrtf(fmaxf(s2 / 64.f - mu * mu, 0.f) + 1e-5f);
        float o0 = p.c2b[0], o1 = p.c2b[1];
        for (int k = 0; k < 64; k++) {
          float zn = (zcl[k] - mu) * rstd * p.clg[k] + p.clb[k];
          o0 += zn * p.c2W[k * 2 + 0];
          o1 += zn * p.c2W[k * 2 + 1];
        }
        p.dout[0] = o0; p.dout[1] = o1;
      }
    }
  }
}

extern "C" void kernel_launch(void* const* d_in, const int* in_sizes, int n_in,
                              void* d_out, int out_size, void* d_ws, size_t ws_size,
                              hipStream_t stream) {
  P p;
  p.x = (const float*)d_in[0];
  const int* ei = (const int*)d_in[1];
  p.N = in_sizes[0] / DIN;
  p.E = in_sizes[1] / 2;
  p.src = ei; p.dst = ei + p.E;
  p.W_in = (const float*)d_in[3]; p.b_in = (const float*)d_in[4];
  p.g1W = (const float*)d_in[5]; p.g1as = (const float*)d_in[6]; p.g1ad = (const float*)d_in[7]; p.g1b = (const float*)d_in[8];
  p.g2W = (const float*)d_in[9]; p.g2as = (const float*)d_in[10]; p.g2ad = (const float*)d_in[11]; p.g2b = (const float*)d_in[12];
  p.g3W = (const float*)d_in[13]; p.g3as = (const float*)d_in[14]; p.g3ad = (const float*)d_in[15]; p.g3b = (const float*)d_in[16];
  p.r1W = (const float*)d_in[17]; p.r1b = (const float*)d_in[18];
  p.r2W = (const float*)d_in[19]; p.r2b = (const float*)d_in[20];
  p.r3W = (const float*)d_in[21]; p.r3b = (const float*)d_in[22];
  p.n1g = (const float*)d_in[23]; p.n1b = (const float*)d_in[24];
  p.n2g = (const float*)d_in[25]; p.n2b = (const float*)d_in[26];
  p.n3g = (const float*)d_in[27]; p.n3b = (const float*)d_in[28];
  p.tw  = (const float*)d_in[29];
  p.c1W = (const float*)d_in[30]; p.c1b = (const float*)d_in[31];
  p.clg = (const float*)d_in[32]; p.clb = (const float*)d_in[33];
  p.c2W = (const float*)d_in[34]; p.c2b = (const float*)d_in[35];
  p.dout = (float*)d_out;

  char* B = (char*)d_ws;
  size_t off = 0;
  auto take = [&](size_t nbytes) -> char* {
    char* r = B + off;
    off += (nbytes + 255) & ~(size_t)255;
    return r;
  };
  p.cnts  = (int*)take(256);
  p.barc  = (int*)take(NBAR * LSTRIDE * 4);
  p.barg  = (int*)take(NLINE * LSTRIDE * 4);
  p.m3    = (int*)take((size_t)3 * p.N * 4);
  p.m2 = p.m3 + p.N; p.m1 = p.m2 + p.N;
  p.tp    = (float*)take((size_t)p.N * TD * 4);
  p.list3 = (int*)take(CAP3 * 4);
  p.list2 = (int*)take(CAP2 * 4);
  p.list1 = (int*)take(CAP1 * 4);
  p.bcnt1 = (int*)take(CAP2 * 4);
  p.bcnt2 = (int*)take(CAP3 * 4);
  p.bcnt3 = (int*)take(64);
  p.bk1   = (int*)take((size_t)CAP2 * BK * 4);
  p.bk2   = (int*)take((size_t)CAP3 * BK * 4);
  p.bk3   = (int*)take(BK * 4);
  p.h0    = (float*)take((size_t)CAP1 * 128 * 4);
  p.hh1   = (float*)take((size_t)CAP1 * 512 * 4);
  p.es1   = (float*)take((size_t)CAP1 * 16);
  p.ed1   = (float*)take((size_t)CAP1 * 16);
  p.h1    = (float*)take((size_t)CAP2 * 128 * 4);
  p.hh2   = (float*)take((size_t)CAP2 * 512 * 4);
  p.es2   = (float*)take((size_t)CAP2 * 16);
  p.ed2   = (float*)take((size_t)CAP2 * 16);
  p.h2    = (float*)take((size_t)CAP3 * 128 * 4);
  p.hh3   = (float*)take((size_t)CAP3 * 256 * 4);
  p.es3   = (float*)take((size_t)CAP3 * 16);
  p.ed3   = (float*)take((size_t)CAP3 * 16);
  p.h3    = (float*)take(64 * 4);

  k_init<<<1024, 256, 0, stream>>>(p);
  k_mega<<<NB, 256, 0, stream>>>(p);
}

// Round 5
// 127.469 us; speedup vs baseline: 3.2858x; 1.3985x over previous
//
#include <hip/hip_runtime.h>

#define AGENT __HIP_MEMORY_SCOPE_AGENT

constexpr int TD = 9, DIN = 135;
constexpr int CAP3 = 256, CAP2 = 1024, CAP1 = 4096, BK = 128;
constexpr int NB = 512;   // 512 blocks x 256 thr; __launch_bounds__(256,2) -> 2 blocks/CU, all co-resident
constexpr int LSTRIDE = 32;               // 128B line spacing for all sync cells
constexpr int NGRP = 16, GSZ = 32;        // arrival tree: 16 groups x 32 blocks
constexpr int NSET = 8;                   // rotating barrier sets (> #barriers, never reused)
constexpr int NLINE = 64;                 // release lines; 8 pollers per line

struct P {
  const float* x; const int* src; const int* dst; int N; int E;
  const float *W_in,*b_in,*g1W,*g1as,*g1ad,*g1b,*g2W,*g2as,*g2ad,*g2b,*g3W,*g3as,*g3ad,*g3b;
  const float *r1W,*r1b,*r2W,*r2b,*r3W,*r3b,*n1g,*n1b,*n2g,*n2b,*n3g,*n3b;
  const float *tw,*c1W,*c1b,*clg,*clb,*c2W,*c2b;
  float* tp;
  int *m3,*m2,*m1,*list3,*list2,*list1,*cnts;  // cnts[0..2]=cnt3/2/1, [8]=simsum(f32), [56]=const 0
  int *barc,*barr,*barg;   // group counters [NSET*NGRP*LSTRIDE], root [NSET*LSTRIDE], release [NLINE*LSTRIDE]
  int *bcnt1,*bcnt2,*bcnt3,*bk1,*bk2,*bk3;
  float *h0,*hh1,*es1,*ed1,*h1,*hh2,*es2,*ed2,*h2,*hh3,*es3,*ed3,*h3;
  float* dout;
};

__device__ __forceinline__ float lrelu(float v) { return v >= 0.f ? v : 0.2f * v; }

// MALL-coherent (cross-XCD visible) relaxed stores; readers in LATER phases may use
// normal cached loads because no normal read of these lines happens before/during the
// writing phase (first normal touch is post-write, post-barrier).
__device__ __forceinline__ void stg(float* pp, float v) { __hip_atomic_store(pp, v, __ATOMIC_RELAXED, AGENT); }
__device__ __forceinline__ void stg(int* pp, int v)   { __hip_atomic_store(pp, v, __ATOMIC_RELAXED, AGENT); }

// CAS-claim node v into (m, list, cnt). m[v] starts -1.
__device__ __forceinline__ void claim_node(int v, int* __restrict__ m, int* __restrict__ list,
                                           int* __restrict__ cnt, int cap) {
  if (atomicCAS(&m[v], -1, -2) == -1) {
    int pos = atomicAdd(cnt, 1);
    if (pos < cap) { stg(&list[pos], v); stg(&m[v], pos); } else { stg(&m[v], -3); }
  }
}

// Fence-free device-scope grid barrier (all data crossing it is MALL-coherent already).
// 2-level arrival tree (16x32 + 16), rotating counter sets, 64 spread release lines.
__device__ __forceinline__ void grid_barrier(const P& p, int& lgen, int* amroot_s) {
  __syncthreads();                         // per-wave vmcnt(0): block's stores reached MALL
  int g = lgen + 1;
  if (threadIdx.x == 0) {
    *amroot_s = 0;
    int grp = blockIdx.x & (NGRP - 1);
    int* gc = &p.barc[(((g & (NSET - 1)) * NGRP) + grp) * LSTRIDE];
    if (__hip_atomic_fetch_add(gc, 1, __ATOMIC_RELAXED, AGENT) == GSZ - 1) {
      int* rc = &p.barr[(g & (NSET - 1)) * LSTRIDE];
      if (__hip_atomic_fetch_add(rc, 1, __ATOMIC_RELAXED, AGENT) == NGRP - 1) *amroot_s = 1;
    }
  }
  __syncthreads();
  if (*amroot_s) {
    if (threadIdx.x < NLINE)
      __hip_atomic_store(&p.barg[threadIdx.x * LSTRIDE], g, __ATOMIC_RELAXED, AGENT);
  } else if (threadIdx.x == 0) {
    int* line = &p.barg[(blockIdx.x & (NLINE - 1)) * LSTRIDE];
    while (__hip_atomic_load(line, __ATOMIC_RELAXED, AGENT) < g)
      __builtin_amdgcn_s_sleep(8);
  }
  __syncthreads();
  lgen = g;
}

// init: maps=-1, counters/barrier state=0, bucket counts=0, pack t = x[:,126:135]
__global__ void k_init(P p) {
  int gt = blockIdx.x * blockDim.x + threadIdx.x;
  int GT = gridDim.x * blockDim.x;
  int n3 = 3 * p.N;
  int4* mv = (int4*)p.m3;             // m3,m2,m1 contiguous
  int4 neg = make_int4(-1, -1, -1, -1);
  int nv = n3 >> 2;
  for (int i = gt; i < nv; i += GT) mv[i] = neg;
  for (int i = (nv << 2) + gt; i < n3; i += GT) p.m3[i] = -1;
  if (gt < 64) p.cnts[gt] = 0;
  for (int i = gt; i < NSET * NGRP * LSTRIDE; i += GT) p.barc[i] = 0;
  for (int i = gt; i < NSET * LSTRIDE; i += GT) p.barr[i] = 0;
  for (int i = gt; i < NLINE * LSTRIDE; i += GT) p.barg[i] = 0;
  for (int i = gt; i < CAP2; i += GT) p.bcnt1[i] = 0;
  for (int i = gt; i < CAP3; i += GT) p.bcnt2[i] = 0;
  if (gt == 0) p.bcnt3[0] = 0;
  int total = p.N * TD;
  for (int i = gt; i < total; i += GT) {
    int v = i / TD, k = i - v * TD;
    p.tp[i] = p.x[(size_t)v * DIN + (DIN - TD) + k];
  }
}

// GAT layer for a compacted dst set (one block per dst node, 256 threads).
template <int C, int ONEXT>
__device__ void gat_phase(int nq, const int* lst, const int* mPrev,
                          const int* bket, const int* bcnt,
                          const float* hh, const float* es, const float* ed, const float* hres,
                          const float* gb, const float* rW, const float* rb,
                          const float* ng, const float* nbv, float scale,
                          float* hout, const float* Wn, const float* avn, const float* bvn,
                          float* hhn, float* esn, float* edn,
                          float* elog, int* eposs, float* sh, float* hres_s, float* shln,
                          float* psn, float* pdn, float* sc2, float* ev_s) {
  const int T = 256, Wd = 4 * C, R = Wd / T;
  int tid = threadIdx.x;
  for (int q = blockIdx.x; q < nq; q += gridDim.x) {
    int v = lst[q];
    int sp = mPrev[v];
    int nb = min(bcnt[q], BK);
    for (int j = tid; j < nb; j += T) {
      int pu = mPrev[bket[(size_t)q * BK + j]];
      eposs[j] = pu;
      const float* ep = &es[(size_t)pu * 4];
      elog[0 * BK + j] = ep[0]; elog[1 * BK + j] = ep[1];
      elog[2 * BK + j] = ep[2]; elog[3 * BK + j] = ep[3];
    }
    if (tid < 4) { ev_s[tid] = es[(size_t)sp * 4 + tid]; ev_s[4 + tid] = ed[(size_t)sp * 4 + tid]; }
    for (int k = tid; k < 128; k += T) hres_s[k] = hres[(size_t)sp * 128 + k];
    __syncthreads();
#pragma unroll
    for (int r = 0; r < R; r++) {
      int w = r * T + tid, a = w / C;
      float edv = ev_s[4 + a];
      float eself = lrelu(ev_s[a] + edv);
      float mx = eself;
      for (int j = 0; j < nb; j++) mx = fmaxf(mx, lrelu(elog[a * BK + j] + edv));
      float den = __expf(eself - mx);
      for (int j = 0; j < nb; j++) den += __expf(lrelu(elog[a * BK + j] + edv) - mx);
      float rden = 1.f / (den + 1e-16f);
      float s = __expf(eself - mx) * rden * hh[(size_t)sp * Wd + w];
      for (int j = 0; j < nb; j++)
        s += __expf(lrelu(elog[a * BK + j] + edv) - mx) * rden * hh[(size_t)eposs[j] * Wd + w];
      sh[w] = s;
    }
    __syncthreads();
    float val = 0.f;
    if (tid < C) {
      float g = 0.25f * (sh[tid] + sh[C + tid] + sh[2 * C + tid] + sh[3 * C + tid]) + gb[tid];
      g *= scale;
      g = fmaxf(g, 0.f);
      float rr = rb[tid];
      for (int k = 0; k < 128; k++) rr += hres_s[k] * rW[(size_t)k * C + tid];
      val = g + rr;
      shln[tid] = val;
    }
    __syncthreads();
    if (tid == 0) {
      float s1 = 0.f, s2 = 0.f;
      for (int k = 0; k < C; k++) { float u = shln[k]; s1 += u; s2 += u * u; }
      float mu = s1 / (float)C;
      sc2[0] = mu;
      sc2[1] = rsqrtf(fmaxf(s2 / (float)C - mu * mu, 0.f) + 1e-5f);
    }
    __syncthreads();
    if (tid < C) {
      float o = (val - sc2[0]) * sc2[1] * ng[tid] + nbv[tid];
      stg(&hout[(size_t)q * C + tid], o);
      shln[tid] = o;
    }
    __syncthreads();
    if (ONEXT > 0) {
      for (int j = tid; j < ONEXT; j += T) {
        float a2 = 0.f;
        for (int k = 0; k < C; k++) a2 += shln[k] * Wn[(size_t)k * ONEXT + j];
        stg(&hhn[(size_t)q * ONEXT + j], a2);
        psn[j] = a2 * avn[j]; pdn[j] = a2 * bvn[j];
      }
      __syncthreads();
      if (tid < 8) {
        const int CN = ONEXT / 4; int a = tid & 3;
        const float* pr = (tid < 4) ? psn : pdn;
        float s = 0.f;
        for (int c = 0; c < CN; c++) s += pr[a * CN + c];
        stg(&(tid < 4 ? esn : edn)[(size_t)q * 4 + a], s);
      }
    }
    __syncthreads();
  }
}

__global__ __launch_bounds__(256, 2) void k_mega(P p) {
  __shared__ float elog[4 * BK];
  __shared__ int   eposs[BK];
  __shared__ float sh[512];
  __shared__ float hres_s[128];
  __shared__ float shln[128];
  __shared__ float psn[512], pdn[512];
  __shared__ float xs[DIN + 1];
  __shared__ float sc2[2];
  __shared__ float ev_s[8];
  __shared__ float wred[4];
  __shared__ float zcl[64];
  __shared__ int   amroot_s;

  int tid = threadIdx.x, bid = blockIdx.x;
  int gt = bid * 256 + tid, GT = gridDim.x * 256;
  int lgen = 0;
  float* simsum = (float*)&p.cnts[8];

  // ---- P1: cosine-sim over all E edges + claim S3 = {0} U N_in(0) ----
  {
    if (gt == 0) claim_node(0, p.m3, p.list3, &p.cnts[0], CAP3);
    float local = 0.f;
    for (int e = gt; e < p.E; e += GT) {
      int s = p.src[e], d = p.dst[e];
      if (d == 0) claim_node(s, p.m3, p.list3, &p.cnts[0], CAP3);
      const float* ti = p.tp + (size_t)s * TD;
      const float* tj = p.tp + (size_t)d * TD;
      float dot = 0.f, na = 0.f, nb2 = 0.f;
#pragma unroll
      for (int k = 0; k < TD; k++) { float a = ti[k], b = tj[k]; dot += a * b; na += a * a; nb2 += b * b; }
      local += dot / (fmaxf(sqrtf(na), 1e-8f) * fmaxf(sqrtf(nb2), 1e-8f));
    }
    for (int off = 32; off > 0; off >>= 1) local += __shfl_down(local, off, 64);
    if ((tid & 63) == 0) wred[tid >> 6] = local;
    __syncthreads();
    if (tid == 0) atomicAdd(simsum, wred[0] + wred[1] + wred[2] + wred[3]);
  }
  grid_barrier(p, lgen, &amroot_s);

  // ---- P2: claim S2 = S3 U N_in(S3) ----
  {
    int c3 = min(__hip_atomic_load(&p.cnts[0], __ATOMIC_RELAXED, AGENT), CAP3);
    for (int i = gt; i < c3; i += GT) claim_node(p.list3[i], p.m2, p.list2, &p.cnts[1], CAP2);
    for (int e = gt; e < p.E; e += GT)
      if (p.m3[p.dst[e]] >= 0) claim_node(p.src[e], p.m2, p.list2, &p.cnts[1], CAP2);
  }
  grid_barrier(p, lgen, &amroot_s);

  // ---- P3: claim S1 = S2 U N_in(S2), and build per-dst edge buckets (raw src ids) ----
  {
    int c2 = min(__hip_atomic_load(&p.cnts[1], __ATOMIC_RELAXED, AGENT), CAP2);
    for (int i = gt; i < c2; i += GT) claim_node(p.list2[i], p.m1, p.list1, &p.cnts[2], CAP1);
    for (int e = gt; e < p.E; e += GT) {
      int s = p.src[e], d = p.dst[e];
      int p2 = p.m2[d];
      if (p2 >= 0) {
        claim_node(s, p.m1, p.list1, &p.cnts[2], CAP1);
        int sl = atomicAdd(&p.bcnt1[p2], 1); if (sl < BK) stg(&p.bk1[(size_t)p2 * BK + sl], s);
      }
      int p3 = p.m3[d];
      if (p3 >= 0) { int sl = atomicAdd(&p.bcnt2[p3], 1); if (sl < BK) stg(&p.bk2[(size_t)p3 * BK + sl], s); }
      if (d == 0)  { int sl = atomicAdd(&p.bcnt3[0], 1);  if (sl < BK) stg(&p.bk3[sl], s); }
    }
  }
  grid_barrier(p, lgen, &amroot_s);

  // ---- P4: per S1 node: h0 = x@W_in+b_in ; hh1 = h0@g1W ; es1/ed1 head sums ----
  {
    int c1 = min(__hip_atomic_load(&p.cnts[2], __ATOMIC_RELAXED, AGENT), CAP1);
    for (int pp = bid; pp < c1; pp += gridDim.x) {
      int v = p.list1[pp];
      for (int k = tid; k < DIN; k += 256) xs[k] = p.x[(size_t)v * DIN + k];
      __syncthreads();
      if (tid < 128) {
        float acc = p.b_in[tid];
        for (int k = 0; k < DIN; k++) acc += xs[k] * p.W_in[(size_t)k * 128 + tid];
        stg(&p.h0[(size_t)pp * 128 + tid], acc);
        hres_s[tid] = acc;
      }
      __syncthreads();
#pragma unroll
      for (int jj = 0; jj < 2; jj++) {
        int j = jj * 256 + tid;
        float acc = 0.f;
        for (int k = 0; k < 128; k++) acc += hres_s[k] * p.g1W[(size_t)k * 512 + j];
        stg(&p.hh1[(size_t)pp * 512 + j], acc);
        psn[j] = acc * p.g1as[j]; pdn[j] = acc * p.g1ad[j];
      }
      __syncthreads();
      if (tid < 8) {
        int a = tid & 3;
        const float* pr = (tid < 4) ? psn : pdn;
        float s = 0.f;
        for (int c = 0; c < 128; c++) s += pr[a * 128 + c];
        stg(&(tid < 4 ? p.es1 : p.ed1)[(size_t)pp * 4 + a], s);
      }
      __syncthreads();
    }
  }
  grid_barrier(p, lgen, &amroot_s);

  int sbits = __hip_atomic_load(&p.cnts[8], __ATOMIC_RELAXED, AGENT);
  float scale = 1.1f + 0.1f * p.tw[0] * __int_as_float(sbits) / (float)p.E;

  // ---- P5: GAT1 over S2 (+ fused proj2) ----
  {
    int c2 = min(__hip_atomic_load(&p.cnts[1], __ATOMIC_RELAXED, AGENT), CAP2);
    gat_phase<128, 512>(c2, p.list2, p.m1, p.bk1, p.bcnt1,
                        p.hh1, p.es1, p.ed1, p.h0,
                        p.g1b, p.r1W, p.r1b, p.n1g, p.n1b, scale,
                        p.h1, p.g2W, p.g2as, p.g2ad, p.hh2, p.es2, p.ed2,
                        elog, eposs, sh, hres_s, shln, psn, pdn, sc2, ev_s);
  }
  grid_barrier(p, lgen, &amroot_s);

  // ---- P6: GAT2 over S3 (+ fused proj3) ----
  {
    int c3 = min(__hip_atomic_load(&p.cnts[0], __ATOMIC_RELAXED, AGENT), CAP3);
    gat_phase<128, 256>(c3, p.list3, p.m2, p.bk2, p.bcnt2,
                        p.hh2, p.es2, p.ed2, p.h1,
                        p.g2b, p.r2W, p.r2b, p.n2g, p.n2b, scale,
                        p.h2, p.g3W, p.g3as, p.g3ad, p.hh3, p.es3, p.ed3,
                        elog, eposs, sh, hres_s, shln, psn, pdn, sc2, ev_s);
  }
  grid_barrier(p, lgen, &amroot_s);

  // ---- P7: GAT3 for node 0 only + classifier (block 0) ----
  {
    gat_phase<64, 0>(1, &p.cnts[56] /* ==0 */, p.m3, p.bk3, p.bcnt3,
                     p.hh3, p.es3, p.ed3, p.h2,
                     p.g3b, p.r3W, p.r3b, p.n3g, p.n3b, 1.f,
                     p.h3, nullptr, nullptr, nullptr, nullptr, nullptr, nullptr,
                     elog, eposs, sh, hres_s, shln, psn, pdn, sc2, ev_s);
    if (bid == 0) {
      if (tid < 64) {
        float az = p.c1b[tid];
        for (int k = 0; k < 64; k++) az += shln[k] * p.c1W[k * 64 + tid];
        zcl[tid] = fmaxf(az, 0.f);
      }
      __syncthreads();
      if (tid == 0) {
        float s1 = 0.f, s2 = 0.f;
        for (int k = 0; k < 64; k++) { float u = zcl[k]; s1 += u; s2 += u * u; }
        float mu = s1 / 64.f;
        float rstd = rsqrtf(fmaxf(s2 / 64.f - mu * mu, 0.f) + 1e-5f);
        float o0 = p.c2b[0], o1 = p.c2b[1];
        for (int k = 0; k < 64; k++) {
          float zn = (zcl[k] - mu) * rstd * p.clg[k] + p.clb[k];
          o0 += zn * p.c2W[k * 2 + 0];
          o1 += zn * p.c2W[k * 2 + 1];
        }
        p.dout[0] = o0; p.dout[1] = o1;
      }
    }
  }
}

extern "C" void kernel_launch(void* const* d_in, const int* in_sizes, int n_in,
                              void* d_out, int out_size, void* d_ws, size_t ws_size,
                              hipStream_t stream) {
  P p;
  p.x = (const float*)d_in[0];
  const int* ei = (const int*)d_in[1];
  p.N = in_sizes[0] / DIN;
  p.E = in_sizes[1] / 2;
  p.src = ei; p.dst = ei + p.E;
  p.W_in = (const float*)d_in[3]; p.b_in = (const float*)d_in[4];
  p.g1W = (const float*)d_in[5]; p.g1as = (const float*)d_in[6]; p.g1ad = (const float*)d_in[7]; p.g1b = (const float*)d_in[8];
  p.g2W = (const float*)d_in[9]; p.g2as = (const float*)d_in[10]; p.g2ad = (const float*)d_in[11]; p.g2b = (const float*)d_in[12];
  p.g3W = (const float*)d_in[13]; p.g3as = (const float*)d_in[14]; p.g3ad = (const float*)d_in[15]; p.g3b = (const float*)d_in[16];
  p.r1W = (const float*)d_in[17]; p.r1b = (const float*)d_in[18];
  p.r2W = (const float*)d_in[19]; p.r2b = (const float*)d_in[20];
  p.r3W = (const float*)d_in[21]; p.r3b = (const float*)d_in[22];
  p.n1g = (const float*)d_in[23]; p.n1b = (const float*)d_in[24];
  p.n2g = (const float*)d_in[25]; p.n2b = (const float*)d_in[26];
  p.n3g = (const float*)d_in[27]; p.n3b = (const float*)d_in[28];
  p.tw  = (const float*)d_in[29];
  p.c1W = (const float*)d_in[30]; p.c1b = (const float*)d_in[31];
  p.clg = (const float*)d_in[32]; p.clb = (const float*)d_in[33];
  p.c2W = (const float*)d_in[34]; p.c2b = (const float*)d_in[35];
  p.dout = (float*)d_out;

  char* B = (char*)d_ws;
  size_t off = 0;
  auto take = [&](size_t nbytes) -> char* {
    char* r = B + off;
    off += (nbytes + 255) & ~(size_t)255;
    return r;
  };
  p.cnts  = (int*)take(256);
  p.barc  = (int*)take((size_t)NSET * NGRP * LSTRIDE * 4);
  p.barr  = (int*)take((size_t)NSET * LSTRIDE * 4);
  p.barg  = (int*)take((size_t)NLINE * LSTRIDE * 4);
  p.m3    = (int*)take((size_t)3 * p.N * 4);
  p.m2 = p.m3 + p.N; p.m1 = p.m2 + p.N;
  p.tp    = (float*)take((size_t)p.N * TD * 4);
  p.list3 = (int*)take(CAP3 * 4);
  p.list2 = (int*)take(CAP2 * 4);
  p.list1 = (int*)take(CAP1 * 4);
  p.bcnt1 = (int*)take(CAP2 * 4);
  p.bcnt2 = (int*)take(CAP3 * 4);
  p.bcnt3 = (int*)take(64);
  p.bk1   = (int*)take((size_t)CAP2 * BK * 4);
  p.bk2   = (int*)take((size_t)CAP3 * BK * 4);
  p.bk3   = (int*)take(BK * 4);
  p.h0    = (float*)take((size_t)CAP1 * 128 * 4);
  p.hh1   = (float*)take((size_t)CAP1 * 512 * 4);
  p.es1   = (float*)take((size_t)CAP1 * 16);
  p.ed1   = (float*)take((size_t)CAP1 * 16);
  p.h1    = (float*)take((size_t)CAP2 * 128 * 4);
  p.hh2   = (float*)take((size_t)CAP2 * 512 * 4);
  p.es2   = (float*)take((size_t)CAP2 * 16);
  p.ed2   = (float*)take((size_t)CAP2 * 16);
  p.h2    = (float*)take((size_t)CAP3 * 128 * 4);
  p.hh3   = (float*)take((size_t)CAP3 * 256 * 4);
  p.es3   = (float*)take((size_t)CAP3 * 16);
  p.ed3   = (float*)take((size_t)CAP3 * 16);
  p.h3    = (float*)take(64 * 4);

  k_init<<<1024, 256, 0, stream>>>(p);
  k_mega<<<NB, 256, 0, stream>>>(p);
}